// Round 25
// baseline (394.517 us; speedup 1.0000x reference)
//
#include <hip/hip_runtime.h>
#include <math.h>

#define N_ATOMS 60000
#define M_NBR   12
#define D_FEA   64
#define NBR_FEA 41
#define B_CRY   1200
#define NA_CRY  50
#define EPSV    1e-5f

#define NBLK_MAIN 2048   // partials rows written by k_stats grid (1280 used)
#define NBLK_ST  1280    // k_stats grid: 5 blocks/CU exactly (256 CU)

typedef _Float16 h2 __attribute__((ext_vector_type(2)));
#define CVTPK(a, b) __builtin_bit_cast(h2, __builtin_amdgcn_cvt_pkrtz((a), (b)))

__device__ __forceinline__ float wsum(float v){
#pragma unroll
  for (int o = 32; o > 0; o >>= 1) v += __shfl_xor(v, o, 64);
  return v;
}
__device__ __forceinline__ float wmax64(float v){
#pragma unroll
  for (int o = 32; o > 0; o >>= 1) v = fmaxf(v, __shfl_xor(v, o, 64));
  return v;
}
__device__ __forceinline__ float softplusf(float x){
  return fmaxf(x, 0.f) + __logf(1.f + __expf(-fabsf(x)));
}
__device__ __forceinline__ float sigmoidf(float x){
  return 1.f / (1.f + __expf(-x));
}
// round-to-nearest-even fp32 -> bf16 bits (low 16)
__device__ __forceinline__ unsigned bf16_rne(float x){
  unsigned u = __float_as_uint(x);
  return (u + 0x7fffu + ((u >> 16) & 1u)) >> 16;
}
__device__ __forceinline__ unsigned pack2(float lo, float hi){
  return bf16_rne(lo) | (bf16_rne(hi) << 16);
}
__device__ __forceinline__ float unlo(unsigned u){ return __uint_as_float(u << 16); }
__device__ __forceinline__ float unhi(unsigned u){ return __uint_as_float(u & 0xffff0000u); }

// ---------------- K0: pre-pack bond weights as f16 k-pairs (r23 proven) -----
__global__ __launch_bounds__(256) void k_prep(
    const float* __restrict__ fc_w, unsigned* __restrict__ wpk)
{
  int t = blockIdx.x * 256 + threadIdx.x;
  if (t >= 21 * 128) return;
  int kk = t >> 7, c = t & 127;
  float lo = fc_w[(128 + 2 * kk) * 128 + c];
  float hi = (kk < 20) ? fc_w[(129 + 2 * kk) * 128 + c] : 0.f;
  wpk[t] = __builtin_bit_cast(unsigned, __builtin_amdgcn_cvt_pkrtz(lo, hi));
}

// ---------------- K1a: attention half (phases 1-5) -> ln1 [N,64] ------------
__global__ __launch_bounds__(512, 4) void k_attn(
    const float* __restrict__ atom_in, const float* __restrict__ adj,
    const float* __restrict__ g1v, const float* __restrict__ be1,
    const int* __restrict__ cidx, float* __restrict__ ln1)
{
  __shared__ float s_a[NA_CRY * D_FEA];        // src rows
  __shared__ float s_b[D_FEA * (NA_CRY + 1)];  // srcT(stride 51) / x
  __shared__ float s_c[NA_CRY * D_FEA];        // scores

  const int tid  = threadIdx.x;
  const int b    = blockIdx.x;
  const int lane = tid & 63;
  const int w    = tid >> 6;   // 0..7

  for (int p = tid; p < NA_CRY * D_FEA; p += 512){
    int i = p >> 6, d = p & 63;
    int a = cidx[b * NA_CRY + i];
    float v = atom_in[(size_t)a * D_FEA + d];
    s_a[p] = v;
    s_b[d * (NA_CRY + 1) + i] = v;
  }
  __syncthreads();

  const float scale = 0.125f; // 1/sqrt(64)
  {
    const float* adjb = adj + (size_t)b * NA_CRY * NA_CRY;
    for (int t = tid; t < 625; t += 512){
      int i0 = (t / 25) * 2, j0 = (t % 25) * 2;
      float a00 = 0.f, a01 = 0.f, a10 = 0.f, a11 = 0.f;
#pragma unroll 8
      for (int d = 0; d < D_FEA; ++d){
        float va0 = s_a[i0 * D_FEA + d];
        float va1 = s_a[(i0 + 1) * D_FEA + d];
        float vb0 = s_b[d * (NA_CRY + 1) + j0];
        float vb1 = s_b[d * (NA_CRY + 1) + j0 + 1];
        a00 += va0 * vb0; a01 += va0 * vb1;
        a10 += va1 * vb0; a11 += va1 * vb1;
      }
      s_c[i0 * NA_CRY + j0]           = a00 * scale * adjb[i0 * NA_CRY + j0];
      s_c[i0 * NA_CRY + j0 + 1]       = a01 * scale * adjb[i0 * NA_CRY + j0 + 1];
      s_c[(i0 + 1) * NA_CRY + j0]     = a10 * scale * adjb[(i0 + 1) * NA_CRY + j0];
      s_c[(i0 + 1) * NA_CRY + j0 + 1] = a11 * scale * adjb[(i0 + 1) * NA_CRY + j0 + 1];
    }
  }
  __syncthreads();

  for (int r = w; r < NA_CRY; r += 8){
    float v = (lane < NA_CRY) ? s_c[r * NA_CRY + lane] : -1e30f;
    float mx = wmax64(v);
    float e = (lane < NA_CRY) ? __expf(v - mx) : 0.f;
    float s = wsum(e);
    if (lane < NA_CRY) s_c[r * NA_CRY + lane] = e / s;
  }
  __syncthreads();

  for (int t = tid; t < 25 * D_FEA; t += 512){
    int nh = t >> 6, d = t & 63;
    int n0 = nh * 2, n1 = n0 + 1;
    float x0 = 0.f, x1 = 0.f;
#pragma unroll 10
    for (int m = 0; m < NA_CRY; ++m){
      float sa = s_a[m * D_FEA + d];
      x0 += s_c[n0 * NA_CRY + m] * sa;
      x1 += s_c[n1 * NA_CRY + m] * sa;
    }
    s_b[n0 * D_FEA + d] = s_a[n0 * D_FEA + d] + x0;
    s_b[n1 * D_FEA + d] = s_a[n1 * D_FEA + d] + x1;
  }
  __syncthreads();

  for (int r = w; r < NA_CRY; r += 8){
    float x = s_b[r * D_FEA + lane];
    float mu = wsum(x) * (1.f / 64.f);
    float dx = x - mu;
    float var = wsum(dx * dx) * (1.f / 64.f);
    ln1[(size_t)(b * NA_CRY + r) * D_FEA + lane] =
        dx * rsqrtf(var + EPSV) * g1v[lane] + be1[lane];
  }
}

// ---------------- K1b: FF + LN2 + projections, barrier-free -----------------
__global__ __launch_bounds__(256) void k_ff(
    const float* __restrict__ ln1, const float* __restrict__ atom_in,
    const int* __restrict__ cidx,
    const float* __restrict__ w1, const float* __restrict__ b1,
    const float* __restrict__ w2, const float* __restrict__ b2,
    const float* __restrict__ g2v, const float* __restrict__ be2,
    const float* __restrict__ fc_w, const float* __restrict__ fc_b,
    float* __restrict__ atom_tf, unsigned* __restrict__ proj1p,
    unsigned* __restrict__ proj2p)
{
  __shared__ float sl[4][8][64];
  const int tid = threadIdx.x, lane = tid & 63, w = tid >> 6;
  float (*A)[64] = &sl[w][0];
  float (*Bs)[64] = &sl[w][4];

  const int gw = blockIdx.x * 4 + w, nw = gridDim.x * 4;
  const int NGRP = N_ATOMS / 4;
  for (int g = gw; g < NGRP; g += nw){
    const int r0 = g * 4;
    float ln0 = ln1[(size_t)(r0 + 0) * 64 + lane];
    float ln1v = ln1[(size_t)(r0 + 1) * 64 + lane];
    float ln2 = ln1[(size_t)(r0 + 2) * 64 + lane];
    float ln3 = ln1[(size_t)(r0 + 3) * 64 + lane];
    A[0][lane] = ln0; A[1][lane] = ln1v; A[2][lane] = ln2; A[3][lane] = ln3;
    __builtin_amdgcn_s_waitcnt(0);

    float h0a = 0.f, h1a = 0.f, h2a = 0.f, h3a = 0.f;
    float h0b = 0.f, h1b = 0.f, h2b = 0.f, h3b = 0.f;
#pragma unroll 8
    for (int k = 0; k < D_FEA; k += 2){
      float wv0 = w1[k * D_FEA + lane];
      float wv1 = w1[(k + 1) * D_FEA + lane];
      h0a += A[0][k] * wv0; h0b += A[0][k + 1] * wv1;
      h1a += A[1][k] * wv0; h1b += A[1][k + 1] * wv1;
      h2a += A[2][k] * wv0; h2b += A[2][k + 1] * wv1;
      h3a += A[3][k] * wv0; h3b += A[3][k + 1] * wv1;
    }
    float bb1 = b1[lane];
    float h0 = fmaxf(bb1 + h0a + h0b, 0.f);
    float h1 = fmaxf(bb1 + h1a + h1b, 0.f);
    float h2 = fmaxf(bb1 + h2a + h2b, 0.f);
    float h3 = fmaxf(bb1 + h3a + h3b, 0.f);
    Bs[0][lane] = h0; Bs[1][lane] = h1; Bs[2][lane] = h2; Bs[3][lane] = h3;
    __builtin_amdgcn_s_waitcnt(0);

    float t0a = 0.f, t1a = 0.f, t2a = 0.f, t3a = 0.f;
    float t0b = 0.f, t1b = 0.f, t2b = 0.f, t3b = 0.f;
#pragma unroll 8
    for (int k = 0; k < D_FEA; k += 2){
      float wv0 = w2[k * D_FEA + lane];
      float wv1 = w2[(k + 1) * D_FEA + lane];
      t0a += Bs[0][k] * wv0; t0b += Bs[0][k + 1] * wv1;
      t1a += Bs[1][k] * wv0; t1b += Bs[1][k + 1] * wv1;
      t2a += Bs[2][k] * wv0; t2b += Bs[2][k + 1] * wv1;
      t3a += Bs[3][k] * wv0; t3b += Bs[3][k + 1] * wv1;
    }
    float bb2 = b2[lane];
    float t0 = ln0 + bb2 + t0a + t0b;
    float t1 = ln1v + bb2 + t1a + t1b;
    float t2 = ln2 + bb2 + t2a + t2b;
    float t3 = ln3 + bb2 + t3a + t3b;

    float gv = g2v[lane], bv = be2[lane];
#define LN2ROW(TT, JJ) { \
      float mu = wsum(TT) * (1.f / 64.f); \
      float dx = (TT) - mu; \
      float var = wsum(dx * dx) * (1.f / 64.f); \
      float res = dx * rsqrtf(var + EPSV) * gv + bv; \
      atom_tf[(size_t)(r0 + JJ) * 64 + lane] = res; \
      A[JJ][lane] = res; }
    LN2ROW(t0, 0) LN2ROW(t1, 1) LN2ROW(t2, 2) LN2ROW(t3, 3)
#undef LN2ROW

    const int ga0 = cidx[r0], ga1 = cidx[r0 + 1], ga2 = cidx[r0 + 2], ga3 = cidx[r0 + 3];
    Bs[0][lane] = atom_in[(size_t)ga0 * 64 + lane];
    Bs[1][lane] = atom_in[(size_t)ga1 * 64 + lane];
    Bs[2][lane] = atom_in[(size_t)ga2 * 64 + lane];
    Bs[3][lane] = atom_in[(size_t)ga3 * 64 + lane];
    __builtin_amdgcn_s_waitcnt(0);

    const float bb0 = fc_b[lane], bb6 = fc_b[64 + lane];
    float A1 = bb0, A2 = bb6, A3 = 0.f, A4 = 0.f;
    float B1 = bb0, B2 = bb6, B3 = 0.f, B4 = 0.f;
    float C1 = bb0, C2 = bb6, C3 = 0.f, C4 = 0.f;
    float D1 = bb0, D2 = bb6, D3 = 0.f, D4 = 0.f;
#pragma unroll 4
    for (int k = 0; k < D_FEA; ++k){
      float w0 = fc_w[k * 128 + lane];
      float w6 = fc_w[k * 128 + 64 + lane];
      float v0 = fc_w[(64 + k) * 128 + lane];
      float v6 = fc_w[(64 + k) * 128 + 64 + lane];
      float ta = A[0][k], tb = A[1][k], tc = A[2][k], td = A[3][k];
      float sa = Bs[0][k], sb = Bs[1][k], sc = Bs[2][k], sd = Bs[3][k];
      A1 += ta * w0; A2 += ta * w6; A3 += sa * v0; A4 += sa * v6;
      B1 += tb * w0; B2 += tb * w6; B3 += sb * v0; B4 += sb * v6;
      C1 += tc * w0; C2 += tc * w6; C3 += sc * v0; C4 += sc * v6;
      D1 += td * w0; D2 += td * w6; D3 += sd * v0; D4 += sd * v6;
    }
    proj1p[(size_t)(r0 + 0) * 64 + lane] = pack2(A1, A2);
    proj1p[(size_t)(r0 + 1) * 64 + lane] = pack2(B1, B2);
    proj1p[(size_t)(r0 + 2) * 64 + lane] = pack2(C1, C2);
    proj1p[(size_t)(r0 + 3) * 64 + lane] = pack2(D1, D2);
    proj2p[(size_t)ga0 * 64 + lane] = pack2(A3, A4);
    proj2p[(size_t)ga1 * 64 + lane] = pack2(B3, B4);
    proj2p[(size_t)ga2 * 64 + lane] = pack2(C3, C4);
    proj2p[(size_t)ga3 * 64 + lane] = pack2(D3, D4);
  }
}

// ---------------- K3: BN1 stats + store pre-BN g (bf16x2) -------------------
// r25: FULL one-atom-ahead pipeline. r24 left the 12 proj2p gathers drained
// in-iteration (~700cy stall each atom; VALU 64%). Now: prologue issues
// atom a0's 13 loads + stage; each iteration waits vmcnt(0) (prev loads,
// hidden under prev compute), copies rn->rc, issues next atom's loads,
// then computes. launch_bounds(256,5): 102-VGPR cap for ~85 live regs;
// grid 1280 = 5 blocks/CU exactly.
#define LOADRWN(MM) rn##MM = proj2p[(size_t)__builtin_amdgcn_readfirstlane(jrow[MM]) * 64 + lane];

#define STAGE(AA, BUF) { \
    const float* srcp = nbr_fea + (size_t)(AA) * (M_NBR * NBR_FEA); \
    float* dstp = s_frow + (w * 2 + (BUF)) * 512; \
    __builtin_amdgcn_global_load_lds(srcp + lane * 4, dstp, 16, 0, 0); \
    if (lane < 59) \
      __builtin_amdgcn_global_load_lds(srcp + 256 + lane * 4, dstp + 256, 16, 0, 0); \
  }

#define GBODY(MM) { \
    float g0 = p10 + unlo(rc##MM); \
    float g1 = p11 + unhi(rc##MM); \
    const float* frm = fr + MM * NBR_FEA; \
    _Pragma("unroll") \
    for (int kk = 0; kk < 20; ++kk){ \
      h2 fa = CVTPK(frm[2 * kk], frm[2 * kk + 1]); \
      g0 = __builtin_amdgcn_fdot2(fa, __builtin_bit_cast(h2, wf0[kk]), g0, false); \
      g1 = __builtin_amdgcn_fdot2(fa, __builtin_bit_cast(h2, wf1[kk]), g1, false); \
    } \
    { h2 fa = CVTPK(frm[40], 0.f); \
      g0 = __builtin_amdgcn_fdot2(fa, __builtin_bit_cast(h2, wf0[20]), g0, false); \
      g1 = __builtin_amdgcn_fdot2(fa, __builtin_bit_cast(h2, wf1[20]), g1, false); } \
    if (STORE) gated[(size_t)(base + MM) * 64 + lane] = pack2(g0, g1); \
    s0 += g0; q0 += g0 * g0; \
    s1 += g1; q1 += g1 * g1; }

template<int STORE>
__global__ __launch_bounds__(256, 5) void k_stats(
    const float* __restrict__ nbr_fea, const int* __restrict__ nbr_idx,
    const unsigned* __restrict__ wpk, const unsigned* __restrict__ proj1p,
    const unsigned* __restrict__ proj2p, float* __restrict__ part1,
    unsigned* __restrict__ gated)
{
  __shared__ float s_frow[4 * 2 * 512];  // staging; reduction aliases after drain
  const int tid = threadIdx.x, lane = tid & 63, w = tid >> 6;

  unsigned wf0[21], wf1[21];
#pragma unroll
  for (int kk = 0; kk < 21; ++kk){
    wf0[kk] = wpk[kk * 128 + lane];
    wf1[kk] = wpk[kk * 128 + 64 + lane];
  }

  const int gw = blockIdx.x * 4 + w, nw = gridDim.x * 4;
  const int q = N_ATOMS / nw, rr = N_ATOMS % nw;
  const int a0 = gw * q + (gw < rr ? gw : rr);
  const int a1 = a0 + q + (gw < rr ? 1 : 0);
  float s0 = 0.f, s1 = 0.f, q0 = 0.f, q1 = 0.f;
  int cur = 0;
  unsigned rn0=0,rn1=0,rn2=0,rn3=0,rn4=0,rn5=0,rn6=0,rn7=0,rn8=0,rn9=0,rn10=0,rn11=0,pn=0;
  if (a0 < a1){
    const int au0 = __builtin_amdgcn_readfirstlane(a0);
    const int* jrow = nbr_idx + au0 * M_NBR;
    pn = proj1p[(size_t)au0 * 64 + lane];
    LOADRWN(0) LOADRWN(1) LOADRWN(2) LOADRWN(3) LOADRWN(4) LOADRWN(5)
    LOADRWN(6) LOADRWN(7) LOADRWN(8) LOADRWN(9) LOADRWN(10) LOADRWN(11)
    STAGE(a0, 0);
  }
  for (int a = a0; a < a1; ++a){
    // wait for current atom's loads (issued previous iteration / prologue)
    asm volatile("s_waitcnt vmcnt(0)" ::: "memory");
    unsigned rc0=rn0, rc1=rn1, rc2=rn2, rc3=rn3, rc4=rn4, rc5=rn5;
    unsigned rc6=rn6, rc7=rn7, rc8=rn8, rc9=rn9, rc10=rn10, rc11=rn11;
    unsigned pc = pn;
    const int au = __builtin_amdgcn_readfirstlane(a);
    const int base = au * M_NBR;
    // issue NEXT atom's loads (fly under this atom's compute)
    const int anext = (a + 1 < a1) ? (a + 1) : a;
    {
      const int aun = __builtin_amdgcn_readfirstlane(anext);
      const int* jrow = nbr_idx + aun * M_NBR;
      pn = proj1p[(size_t)aun * 64 + lane];
      LOADRWN(0) LOADRWN(1) LOADRWN(2) LOADRWN(3) LOADRWN(4) LOADRWN(5)
      LOADRWN(6) LOADRWN(7) LOADRWN(8) LOADRWN(9) LOADRWN(10) LOADRWN(11)
      STAGE(anext, cur ^ 1);
    }
    const float* fr = s_frow + (w * 2 + cur) * 512;
    const float p10 = unlo(pc), p11 = unhi(pc);
    GBODY(0) GBODY(1) GBODY(2) GBODY(3) GBODY(4) GBODY(5)
    GBODY(6) GBODY(7) GBODY(8) GBODY(9) GBODY(10) GBODY(11)
    cur ^= 1;
  }
  // drain ALL pending loads (incl. dummy last-stage) before aliasing s_frow
  asm volatile("s_waitcnt vmcnt(0)" ::: "memory");
  __syncthreads();
  float* red = s_frow;
  red[w * 256 + lane]        = s0;
  red[w * 256 + 64 + lane]   = s1;
  red[w * 256 + 128 + lane]  = q0;
  red[w * 256 + 192 + lane]  = q1;
  __syncthreads();
  float v = red[tid] + red[256 + tid] + red[512 + tid] + red[768 + tid];
  part1[blockIdx.x * 256 + tid] = v;
}

// ---- parallel BN1 finish: 128 blocks (r21 proven) --------------------------
__global__ __launch_bounds__(256) void k_stats_fin(
    const float* __restrict__ part1, const float* __restrict__ bn1_g,
    const float* __restrict__ bn1_b, float* __restrict__ stats1)
{
  __shared__ float red[256];
  const int c = blockIdx.x;
  const int t = threadIdx.x;
  float s = 0.f, q = 0.f;
#pragma unroll
  for (int i = t; i < NBLK_ST; i += 256){
    s += part1[(size_t)i * 256 + c];
    q += part1[(size_t)i * 256 + 128 + c];
  }
  red[t] = s; __syncthreads();
  for (int o = 128; o > 0; o >>= 1){ if (t < o) red[t] += red[t + o]; __syncthreads(); }
  float sumv = red[0]; __syncthreads();
  red[t] = q; __syncthreads();
  for (int o = 128; o > 0; o >>= 1){ if (t < o) red[t] += red[t + o]; __syncthreads(); }
  if (t == 0){
    const float inv = 1.f / (float)(N_ATOMS * M_NBR);
    float mu = sumv * inv;
    float var = red[0] * inv - mu * mu;
    float sc = bn1_g[c] * rsqrtf(var + EPSV);
    stats1[c] = sc;
    stats1[128 + c] = bn1_b[c] - mu * sc;
  }
}

// ---------------- K4a (gated path): streaming BN1+gate+sum ------------------
__global__ __launch_bounds__(256) void k_reduce_g(
    const unsigned* __restrict__ gated, const float* __restrict__ stats1,
    float* __restrict__ nbr_sumed, float* __restrict__ part2)
{
  __shared__ float red[512];
  const int tid = threadIdx.x, lane = tid & 63, w = tid >> 6;
  const float sc0 = stats1[lane],       sc1 = stats1[64 + lane];
  const float tc0 = stats1[128 + lane], tc1 = stats1[192 + lane];
  const int wg = blockIdx.x * 4 + w, nw = gridDim.x * 4;
  float bs = 0.f, bq = 0.f;
  for (int a = wg; a < N_ATOMS; a += nw){
    const size_t base = (size_t)a * M_NBR * 64 + lane;
    float acc = 0.f;
#pragma unroll
    for (int m = 0; m < M_NBR; ++m){
      unsigned gv = gated[base + m * 64];
      acc += sigmoidf(unlo(gv) * sc0 + tc0) * softplusf(unhi(gv) * sc1 + tc1);
    }
    nbr_sumed[(size_t)a * 64 + lane] = acc;
    bs += acc; bq += acc * acc;
  }
  red[w * 128 + lane]      = bs;
  red[w * 128 + 64 + lane] = bq;
  __syncthreads();
  if (tid < 128){
    float v = red[tid] + red[128 + tid] + red[256 + tid] + red[384 + tid];
    part2[blockIdx.x * 128 + tid] = v;
  }
}

// ---------------- K4b (fallback): recompute g, BN1, gate, sum ---------------
#define LOADRW(MM) unsigned rw##MM = proj2p[(size_t)__builtin_amdgcn_readfirstlane(jrow[MM]) * 64 + lane];
#define GBODYR(MM) { \
    const float* frow = nbr_fea + (size_t)(base + MM) * NBR_FEA; \
    float g0 = p10 + unlo(rw##MM); \
    float g1 = p11 + unhi(rw##MM); \
    _Pragma("unroll") \
    for (int k = 0; k < NBR_FEA; ++k){ \
      float aa = frow[k]; \
      g0 += aa * unlo(wbp[k]); \
      g1 += aa * unhi(wbp[k]); \
    } \
    acc += sigmoidf(g0 * sc0 + tc0) * softplusf(g1 * sc1 + tc1); }

__global__ __launch_bounds__(256) void k_reduce_r(
    const float* __restrict__ nbr_fea, const int* __restrict__ nbr_idx,
    const float* __restrict__ fc_w, const unsigned* __restrict__ proj1p,
    const unsigned* __restrict__ proj2p, const float* __restrict__ stats1,
    float* __restrict__ nbr_sumed, float* __restrict__ part2)
{
  __shared__ float red[512];
  const int tid = threadIdx.x, lane = tid & 63, w = tid >> 6;
  unsigned wbp[NBR_FEA];
#pragma unroll
  for (int k = 0; k < NBR_FEA; ++k){
    float w0 = fc_w[(128 + k) * 128 + lane];
    float w1 = fc_w[(128 + k) * 128 + 64 + lane];
    wbp[k] = pack2(w0, w1);
  }
  const float sc0 = stats1[lane],       sc1 = stats1[64 + lane];
  const float tc0 = stats1[128 + lane], tc1 = stats1[192 + lane];
  const int gw = blockIdx.x * 4 + w, nw = gridDim.x * 4;
  const int q = N_ATOMS / nw, rr = N_ATOMS % nw;
  const int a0 = gw * q + (gw < rr ? gw : rr);
  const int a1 = a0 + q + (gw < rr ? 1 : 0);
  float bs = 0.f, bq = 0.f;
  for (int a = a0; a < a1; ++a){
    const int au = __builtin_amdgcn_readfirstlane(a);
    const int base = au * M_NBR;
    const int* jrow = nbr_idx + base;
    unsigned p1v = proj1p[(size_t)au * 64 + lane];
    LOADRW(0) LOADRW(1) LOADRW(2) LOADRW(3) LOADRW(4) LOADRW(5)
    LOADRW(6) LOADRW(7) LOADRW(8) LOADRW(9) LOADRW(10) LOADRW(11)
    const float p10 = unlo(p1v), p11 = unhi(p1v);
    float acc = 0.f;
    GBODYR(0) GBODYR(1) GBODYR(2) GBODYR(3) GBODYR(4) GBODYR(5)
    GBODYR(6) GBODYR(7) GBODYR(8) GBODYR(9) GBODYR(10) GBODYR(11)
    nbr_sumed[(size_t)au * 64 + lane] = acc;
    bs += acc; bq += acc * acc;
  }
  red[w * 128 + lane]      = bs;
  red[w * 128 + 64 + lane] = bq;
  __syncthreads();
  if (tid < 128){
    float v = red[tid] + red[128 + tid] + red[256 + tid] + red[384 + tid];
    part2[blockIdx.x * 128 + tid] = v;
  }
}

// ---- parallel BN2 finish: 64 blocks (r21 proven) ---------------------------
__global__ __launch_bounds__(256) void k_red_fin(
    const float* __restrict__ part2, const float* __restrict__ bn2_g,
    const float* __restrict__ bn2_b, float* __restrict__ stats2)
{
  __shared__ float red[256];
  const int c = blockIdx.x;
  const int t = threadIdx.x;
  float s = 0.f, q = 0.f;
#pragma unroll
  for (int i = t; i < NBLK_MAIN; i += 256){
    s += part2[(size_t)i * 128 + c];
    q += part2[(size_t)i * 128 + 64 + c];
  }
  red[t] = s; __syncthreads();
  for (int o = 128; o > 0; o >>= 1){ if (t < o) red[t] += red[t + o]; __syncthreads(); }
  float sumv = red[0]; __syncthreads();
  red[t] = q; __syncthreads();
  for (int o = 128; o > 0; o >>= 1){ if (t < o) red[t] += red[t + o]; __syncthreads(); }
  if (t == 0){
    const float inv = 1.f / (float)N_ATOMS;
    float mu = sumv * inv;
    float var = red[0] * inv - mu * mu;
    float sc = bn2_g[c] * rsqrtf(var + EPSV);
    stats2[c] = sc;
    stats2[64 + c] = bn2_b[c] - mu * sc;
  }
}

// ---------------- K5: out = softplus(atom_tf + BN2(nbr_sumed)), float4 ------
__global__ __launch_bounds__(256) void k_final(
    const float* __restrict__ atom_tf, const float* __restrict__ ns,
    const float* __restrict__ stats2, float* __restrict__ out)
{
  int i = blockIdx.x * 256 + threadIdx.x;   // one float4 per thread
  if (i >= N_ATOMS * 16) return;            // N*64/4
  int c0 = (i * 4) & 63;
  float4 av = ((const float4*)atom_tf)[i];
  float4 nv = ((const float4*)ns)[i];
  float4 o;
  o.x = softplusf(av.x + nv.x * stats2[c0]     + stats2[64 + c0]);
  o.y = softplusf(av.y + nv.y * stats2[c0 + 1] + stats2[64 + c0 + 1]);
  o.z = softplusf(av.z + nv.z * stats2[c0 + 2] + stats2[64 + c0 + 2]);
  o.w = softplusf(av.w + nv.w * stats2[c0 + 3] + stats2[64 + c0 + 3]);
  ((float4*)out)[i] = o;
}

extern "C" void kernel_launch(void* const* d_in, const int* in_sizes, int n_in,
                              void* d_out, int out_size, void* d_ws, size_t ws_size,
                              hipStream_t stream)
{
  const float* atom_in = (const float*)d_in[0];
  const float* nbr_fea = (const float*)d_in[1];
  const float* adj     = (const float*)d_in[2];
  const float* w1 = (const float*)d_in[3];
  const float* b1 = (const float*)d_in[4];
  const float* w2 = (const float*)d_in[5];
  const float* b2 = (const float*)d_in[6];
  const float* tln1_g = (const float*)d_in[7];
  const float* tln1_b = (const float*)d_in[8];
  const float* tln2_g = (const float*)d_in[9];
  const float* tln2_b = (const float*)d_in[10];
  const float* fc_w = (const float*)d_in[11];
  const float* fc_b = (const float*)d_in[12];
  const float* bn1_g = (const float*)d_in[13];
  const float* bn1_b = (const float*)d_in[14];
  const float* bn2_g = (const float*)d_in[15];
  const float* bn2_b = (const float*)d_in[16];
  const int* nbr_idx = (const int*)d_in[17];
  const int* cidx    = (const int*)d_in[18];
  float* out = (float*)d_out;

  char* ws = (char*)d_ws;
  size_t off = 0;
  float* atom_tf = (float*)(ws + off);    off += (size_t)N_ATOMS * 64 * 4;
  unsigned* proj1p = (unsigned*)(ws + off); off += (size_t)N_ATOMS * 64 * 4;
  unsigned* proj2p = (unsigned*)(ws + off); off += (size_t)N_ATOMS * 64 * 4;
  float* nbr_sumed = (float*)(ws + off);  off += (size_t)N_ATOMS * 64 * 4;
  float* part1 = (float*)(ws + off);      off += (size_t)NBLK_MAIN * 256 * 4;
  float* stats1 = (float*)(ws + off);     off += 256 * 4;
  float* part2 = (float*)(ws + off);      off += (size_t)NBLK_MAIN * 128 * 4;
  float* stats2 = (float*)(ws + off);     off += 128 * 4;
  unsigned* wpk = (unsigned*)(ws + off);  off += 21 * 128 * 4;
  unsigned* gated = (unsigned*)(ws + off);
  const size_t need_gated = off + (size_t)N_ATOMS * M_NBR * 64 * 4;
  const bool use_gated = (ws_size >= need_gated);

  float* ln1 = nbr_sumed;

  k_prep<<<11, 256, 0, stream>>>(fc_w, wpk);
  k_attn<<<B_CRY, 512, 0, stream>>>(atom_in, adj, tln1_g, tln1_b, cidx, ln1);
  k_ff<<<2048, 256, 0, stream>>>(ln1, atom_in, cidx, w1, b1, w2, b2,
      tln2_g, tln2_b, fc_w, fc_b, atom_tf, proj1p, proj2p);
  if (use_gated){
    k_stats<1><<<NBLK_ST, 256, 0, stream>>>(nbr_fea, nbr_idx, wpk, proj1p,
        proj2p, part1, gated);
    k_stats_fin<<<128, 256, 0, stream>>>(part1, bn1_g, bn1_b, stats1);
    k_reduce_g<<<NBLK_MAIN, 256, 0, stream>>>(gated, stats1, nbr_sumed, part2);
  } else {
    k_stats<0><<<NBLK_ST, 256, 0, stream>>>(nbr_fea, nbr_idx, wpk, proj1p,
        proj2p, part1, gated);
    k_stats_fin<<<128, 256, 0, stream>>>(part1, bn1_g, bn1_b, stats1);
    k_reduce_r<<<NBLK_MAIN, 256, 0, stream>>>(nbr_fea, nbr_idx, fc_w, proj1p,
        proj2p, stats1, nbr_sumed, part2);
  }
  k_red_fin<<<64, 256, 0, stream>>>(part2, bn2_g, bn2_b, stats2);
  k_final<<<(N_ATOMS * 16 + 255) / 256, 256, 0, stream>>>(atom_tf, nbr_sumed, stats2, out);
}

// Round 26
// 346.764 us; speedup vs baseline: 1.1377x; 1.1377x over previous
//
#include <hip/hip_runtime.h>
#include <math.h>

#define N_ATOMS 60000
#define M_NBR   12
#define D_FEA   64
#define NBR_FEA 41
#define B_CRY   1200
#define NA_CRY  50
#define EPSV    1e-5f

#define NBLK_MAIN 2048   // partials allocation size
#define NBLK_ST  1024    // k_stats grid: 4 blocks/CU exactly (40KB LDS each)

typedef _Float16 h2 __attribute__((ext_vector_type(2)));
#define CVTPK(a, b) __builtin_bit_cast(h2, __builtin_amdgcn_cvt_pkrtz((a), (b)))

__device__ __forceinline__ float wsum(float v){
#pragma unroll
  for (int o = 32; o > 0; o >>= 1) v += __shfl_xor(v, o, 64);
  return v;
}
__device__ __forceinline__ float wmax64(float v){
#pragma unroll
  for (int o = 32; o > 0; o >>= 1) v = fmaxf(v, __shfl_xor(v, o, 64));
  return v;
}
__device__ __forceinline__ float softplusf(float x){
  return fmaxf(x, 0.f) + __logf(1.f + __expf(-fabsf(x)));
}
__device__ __forceinline__ float sigmoidf(float x){
  return 1.f / (1.f + __expf(-x));
}
// round-to-nearest-even fp32 -> bf16 bits (low 16)
__device__ __forceinline__ unsigned bf16_rne(float x){
  unsigned u = __float_as_uint(x);
  return (u + 0x7fffu + ((u >> 16) & 1u)) >> 16;
}
__device__ __forceinline__ unsigned pack2(float lo, float hi){
  return bf16_rne(lo) | (bf16_rne(hi) << 16);
}
__device__ __forceinline__ float unlo(unsigned u){ return __uint_as_float(u << 16); }
__device__ __forceinline__ float unhi(unsigned u){ return __uint_as_float(u & 0xffff0000u); }

// ---------------- K0: pre-pack bond weights as f16 k-pairs (r23 proven) -----
__global__ __launch_bounds__(256) void k_prep(
    const float* __restrict__ fc_w, unsigned* __restrict__ wpk)
{
  int t = blockIdx.x * 256 + threadIdx.x;
  if (t >= 21 * 128) return;
  int kk = t >> 7, c = t & 127;
  float lo = fc_w[(128 + 2 * kk) * 128 + c];
  float hi = (kk < 20) ? fc_w[(129 + 2 * kk) * 128 + c] : 0.f;
  wpk[t] = __builtin_bit_cast(unsigned, __builtin_amdgcn_cvt_pkrtz(lo, hi));
}

// ---------------- K1a: attention half (phases 1-5) -> ln1 [N,64] ------------
__global__ __launch_bounds__(512, 4) void k_attn(
    const float* __restrict__ atom_in, const float* __restrict__ adj,
    const float* __restrict__ g1v, const float* __restrict__ be1,
    const int* __restrict__ cidx, float* __restrict__ ln1)
{
  __shared__ float s_a[NA_CRY * D_FEA];        // src rows
  __shared__ float s_b[D_FEA * (NA_CRY + 1)];  // srcT(stride 51) / x
  __shared__ float s_c[NA_CRY * D_FEA];        // scores

  const int tid  = threadIdx.x;
  const int b    = blockIdx.x;
  const int lane = tid & 63;
  const int w    = tid >> 6;   // 0..7

  for (int p = tid; p < NA_CRY * D_FEA; p += 512){
    int i = p >> 6, d = p & 63;
    int a = cidx[b * NA_CRY + i];
    float v = atom_in[(size_t)a * D_FEA + d];
    s_a[p] = v;
    s_b[d * (NA_CRY + 1) + i] = v;
  }
  __syncthreads();

  const float scale = 0.125f; // 1/sqrt(64)
  {
    const float* adjb = adj + (size_t)b * NA_CRY * NA_CRY;
    for (int t = tid; t < 625; t += 512){
      int i0 = (t / 25) * 2, j0 = (t % 25) * 2;
      float a00 = 0.f, a01 = 0.f, a10 = 0.f, a11 = 0.f;
#pragma unroll 8
      for (int d = 0; d < D_FEA; ++d){
        float va0 = s_a[i0 * D_FEA + d];
        float va1 = s_a[(i0 + 1) * D_FEA + d];
        float vb0 = s_b[d * (NA_CRY + 1) + j0];
        float vb1 = s_b[d * (NA_CRY + 1) + j0 + 1];
        a00 += va0 * vb0; a01 += va0 * vb1;
        a10 += va1 * vb0; a11 += va1 * vb1;
      }
      s_c[i0 * NA_CRY + j0]           = a00 * scale * adjb[i0 * NA_CRY + j0];
      s_c[i0 * NA_CRY + j0 + 1]       = a01 * scale * adjb[i0 * NA_CRY + j0 + 1];
      s_c[(i0 + 1) * NA_CRY + j0]     = a10 * scale * adjb[(i0 + 1) * NA_CRY + j0];
      s_c[(i0 + 1) * NA_CRY + j0 + 1] = a11 * scale * adjb[(i0 + 1) * NA_CRY + j0 + 1];
    }
  }
  __syncthreads();

  for (int r = w; r < NA_CRY; r += 8){
    float v = (lane < NA_CRY) ? s_c[r * NA_CRY + lane] : -1e30f;
    float mx = wmax64(v);
    float e = (lane < NA_CRY) ? __expf(v - mx) : 0.f;
    float s = wsum(e);
    if (lane < NA_CRY) s_c[r * NA_CRY + lane] = e / s;
  }
  __syncthreads();

  for (int t = tid; t < 25 * D_FEA; t += 512){
    int nh = t >> 6, d = t & 63;
    int n0 = nh * 2, n1 = n0 + 1;
    float x0 = 0.f, x1 = 0.f;
#pragma unroll 10
    for (int m = 0; m < NA_CRY; ++m){
      float sa = s_a[m * D_FEA + d];
      x0 += s_c[n0 * NA_CRY + m] * sa;
      x1 += s_c[n1 * NA_CRY + m] * sa;
    }
    s_b[n0 * D_FEA + d] = s_a[n0 * D_FEA + d] + x0;
    s_b[n1 * D_FEA + d] = s_a[n1 * D_FEA + d] + x1;
  }
  __syncthreads();

  for (int r = w; r < NA_CRY; r += 8){
    float x = s_b[r * D_FEA + lane];
    float mu = wsum(x) * (1.f / 64.f);
    float dx = x - mu;
    float var = wsum(dx * dx) * (1.f / 64.f);
    ln1[(size_t)(b * NA_CRY + r) * D_FEA + lane] =
        dx * rsqrtf(var + EPSV) * g1v[lane] + be1[lane];
  }
}

// ---------------- K1b: FF + LN2 + projections, barrier-free -----------------
__global__ __launch_bounds__(256) void k_ff(
    const float* __restrict__ ln1, const float* __restrict__ atom_in,
    const int* __restrict__ cidx,
    const float* __restrict__ w1, const float* __restrict__ b1,
    const float* __restrict__ w2, const float* __restrict__ b2,
    const float* __restrict__ g2v, const float* __restrict__ be2,
    const float* __restrict__ fc_w, const float* __restrict__ fc_b,
    float* __restrict__ atom_tf, unsigned* __restrict__ proj1p,
    unsigned* __restrict__ proj2p)
{
  __shared__ float sl[4][8][64];
  const int tid = threadIdx.x, lane = tid & 63, w = tid >> 6;
  float (*A)[64] = &sl[w][0];
  float (*Bs)[64] = &sl[w][4];

  const int gw = blockIdx.x * 4 + w, nw = gridDim.x * 4;
  const int NGRP = N_ATOMS / 4;
  for (int g = gw; g < NGRP; g += nw){
    const int r0 = g * 4;
    float ln0 = ln1[(size_t)(r0 + 0) * 64 + lane];
    float ln1v = ln1[(size_t)(r0 + 1) * 64 + lane];
    float ln2 = ln1[(size_t)(r0 + 2) * 64 + lane];
    float ln3 = ln1[(size_t)(r0 + 3) * 64 + lane];
    A[0][lane] = ln0; A[1][lane] = ln1v; A[2][lane] = ln2; A[3][lane] = ln3;
    __builtin_amdgcn_s_waitcnt(0);

    float h0a = 0.f, h1a = 0.f, h2a = 0.f, h3a = 0.f;
    float h0b = 0.f, h1b = 0.f, h2b = 0.f, h3b = 0.f;
#pragma unroll 8
    for (int k = 0; k < D_FEA; k += 2){
      float wv0 = w1[k * D_FEA + lane];
      float wv1 = w1[(k + 1) * D_FEA + lane];
      h0a += A[0][k] * wv0; h0b += A[0][k + 1] * wv1;
      h1a += A[1][k] * wv0; h1b += A[1][k + 1] * wv1;
      h2a += A[2][k] * wv0; h2b += A[2][k + 1] * wv1;
      h3a += A[3][k] * wv0; h3b += A[3][k + 1] * wv1;
    }
    float bb1 = b1[lane];
    float h0 = fmaxf(bb1 + h0a + h0b, 0.f);
    float h1 = fmaxf(bb1 + h1a + h1b, 0.f);
    float h2 = fmaxf(bb1 + h2a + h2b, 0.f);
    float h3 = fmaxf(bb1 + h3a + h3b, 0.f);
    Bs[0][lane] = h0; Bs[1][lane] = h1; Bs[2][lane] = h2; Bs[3][lane] = h3;
    __builtin_amdgcn_s_waitcnt(0);

    float t0a = 0.f, t1a = 0.f, t2a = 0.f, t3a = 0.f;
    float t0b = 0.f, t1b = 0.f, t2b = 0.f, t3b = 0.f;
#pragma unroll 8
    for (int k = 0; k < D_FEA; k += 2){
      float wv0 = w2[k * D_FEA + lane];
      float wv1 = w2[(k + 1) * D_FEA + lane];
      t0a += Bs[0][k] * wv0; t0b += Bs[0][k + 1] * wv1;
      t1a += Bs[1][k] * wv0; t1b += Bs[1][k + 1] * wv1;
      t2a += Bs[2][k] * wv0; t2b += Bs[2][k + 1] * wv1;
      t3a += Bs[3][k] * wv0; t3b += Bs[3][k + 1] * wv1;
    }
    float bb2 = b2[lane];
    float t0 = ln0 + bb2 + t0a + t0b;
    float t1 = ln1v + bb2 + t1a + t1b;
    float t2 = ln2 + bb2 + t2a + t2b;
    float t3 = ln3 + bb2 + t3a + t3b;

    float gv = g2v[lane], bv = be2[lane];
#define LN2ROW(TT, JJ) { \
      float mu = wsum(TT) * (1.f / 64.f); \
      float dx = (TT) - mu; \
      float var = wsum(dx * dx) * (1.f / 64.f); \
      float res = dx * rsqrtf(var + EPSV) * gv + bv; \
      atom_tf[(size_t)(r0 + JJ) * 64 + lane] = res; \
      A[JJ][lane] = res; }
    LN2ROW(t0, 0) LN2ROW(t1, 1) LN2ROW(t2, 2) LN2ROW(t3, 3)
#undef LN2ROW

    const int ga0 = cidx[r0], ga1 = cidx[r0 + 1], ga2 = cidx[r0 + 2], ga3 = cidx[r0 + 3];
    Bs[0][lane] = atom_in[(size_t)ga0 * 64 + lane];
    Bs[1][lane] = atom_in[(size_t)ga1 * 64 + lane];
    Bs[2][lane] = atom_in[(size_t)ga2 * 64 + lane];
    Bs[3][lane] = atom_in[(size_t)ga3 * 64 + lane];
    __builtin_amdgcn_s_waitcnt(0);

    const float bb0 = fc_b[lane], bb6 = fc_b[64 + lane];
    float A1 = bb0, A2 = bb6, A3 = 0.f, A4 = 0.f;
    float B1 = bb0, B2 = bb6, B3 = 0.f, B4 = 0.f;
    float C1 = bb0, C2 = bb6, C3 = 0.f, C4 = 0.f;
    float D1 = bb0, D2 = bb6, D3 = 0.f, D4 = 0.f;
#pragma unroll 4
    for (int k = 0; k < D_FEA; ++k){
      float w0 = fc_w[k * 128 + lane];
      float w6 = fc_w[k * 128 + 64 + lane];
      float v0 = fc_w[(64 + k) * 128 + lane];
      float v6 = fc_w[(64 + k) * 128 + 64 + lane];
      float ta = A[0][k], tb = A[1][k], tc = A[2][k], td = A[3][k];
      float sa = Bs[0][k], sb = Bs[1][k], sc = Bs[2][k], sd = Bs[3][k];
      A1 += ta * w0; A2 += ta * w6; A3 += sa * v0; A4 += sa * v6;
      B1 += tb * w0; B2 += tb * w6; B3 += sb * v0; B4 += sb * v6;
      C1 += tc * w0; C2 += tc * w6; C3 += sc * v0; C4 += sc * v6;
      D1 += td * w0; D2 += td * w6; D3 += sd * v0; D4 += sd * v6;
    }
    proj1p[(size_t)(r0 + 0) * 64 + lane] = pack2(A1, A2);
    proj1p[(size_t)(r0 + 1) * 64 + lane] = pack2(B1, B2);
    proj1p[(size_t)(r0 + 2) * 64 + lane] = pack2(C1, C2);
    proj1p[(size_t)(r0 + 3) * 64 + lane] = pack2(D1, D2);
    proj2p[(size_t)ga0 * 64 + lane] = pack2(A3, A4);
    proj2p[(size_t)ga1 * 64 + lane] = pack2(B3, B4);
    proj2p[(size_t)ga2 * 64 + lane] = pack2(C3, C4);
    proj2p[(size_t)ga3 * 64 + lane] = pack2(D3, D4);
  }
}

// ---------------- K3: BN1 stats + store pre-BN g (bf16x2) -------------------
// r26: LDS-DMA pipeline. r25's register pipeline spilled (26 live regs over
// budget -> VGPR 48, 360MB scratch). Now ALL per-atom data (features + 12
// proj2p rows) is DMA'd via global_load_lds into a 1280-float wave-private
// double buffer -- ZERO pipeline registers. proj2p rows are wave-uniform
// base + lane*4B = exactly the legal DMA pattern (16 lanes x 16B per row).
// Steady-state wait vmcnt(12) (12 newest = prev body's gated stores; the 15
// older DMA/loads for the current buffer are then guaranteed complete).
#define STAGEA(AA, BUF) { \
    const float* srcp = nbr_fea + (size_t)(AA) * (M_NBR * NBR_FEA); \
    float* dstp = s_frow + (w * 2 + (BUF)) * 1280; \
    __builtin_amdgcn_global_load_lds(srcp + lane * 4, dstp, 16, 0, 0); \
    if (lane < 59) \
      __builtin_amdgcn_global_load_lds(srcp + 256 + lane * 4, dstp + 256, 16, 0, 0); \
  }

#define STAGEP(JV, MM, BUF) { \
    const float* srcp = (const float*)(proj2p + (size_t)__builtin_amdgcn_readfirstlane(JV) * 64); \
    float* dstp = s_frow + (w * 2 + (BUF)) * 1280 + 512 + MM * 64; \
    if (lane < 16) \
      __builtin_amdgcn_global_load_lds(srcp + lane * 4, dstp, 16, 0, 0); \
  }

#define GBODY(MM) { \
    unsigned rcv = fr2[MM * 64 + lane]; \
    float g0 = p10 + unlo(rcv); \
    float g1 = p11 + unhi(rcv); \
    const float* frm = fr + MM * NBR_FEA; \
    _Pragma("unroll") \
    for (int kk = 0; kk < 20; ++kk){ \
      h2 fa = CVTPK(frm[2 * kk], frm[2 * kk + 1]); \
      g0 = __builtin_amdgcn_fdot2(fa, __builtin_bit_cast(h2, wf0[kk]), g0, false); \
      g1 = __builtin_amdgcn_fdot2(fa, __builtin_bit_cast(h2, wf1[kk]), g1, false); \
    } \
    { h2 fa = CVTPK(frm[40], 0.f); \
      g0 = __builtin_amdgcn_fdot2(fa, __builtin_bit_cast(h2, wf0[20]), g0, false); \
      g1 = __builtin_amdgcn_fdot2(fa, __builtin_bit_cast(h2, wf1[20]), g1, false); } \
    if (STORE) gated[(size_t)(base + MM) * 64 + lane] = pack2(g0, g1); \
    s0 += g0; q0 += g0 * g0; \
    s1 += g1; q1 += g1 * g1; }

#define ISSUE_ATOM(AA, BUF) { \
    const int auI = __builtin_amdgcn_readfirstlane(AA); \
    const int* jrow = nbr_idx + auI * M_NBR; \
    STAGEA(auI, BUF); \
    STAGEP(jrow[0], 0, BUF)  STAGEP(jrow[1], 1, BUF)  STAGEP(jrow[2], 2, BUF) \
    STAGEP(jrow[3], 3, BUF)  STAGEP(jrow[4], 4, BUF)  STAGEP(jrow[5], 5, BUF) \
    STAGEP(jrow[6], 6, BUF)  STAGEP(jrow[7], 7, BUF)  STAGEP(jrow[8], 8, BUF) \
    STAGEP(jrow[9], 9, BUF)  STAGEP(jrow[10], 10, BUF) STAGEP(jrow[11], 11, BUF) \
    pn = proj1p[(size_t)auI * 64 + lane]; \
  }

template<int STORE>
__global__ __launch_bounds__(256) void k_stats(
    const float* __restrict__ nbr_fea, const int* __restrict__ nbr_idx,
    const unsigned* __restrict__ wpk, const unsigned* __restrict__ proj1p,
    const unsigned* __restrict__ proj2p, float* __restrict__ part1,
    unsigned* __restrict__ gated)
{
  __shared__ float s_frow[4 * 2 * 1280];  // 40KB: 4 waves x dbuf x (492 fea + 768 proj2)
  const int tid = threadIdx.x, lane = tid & 63, w = tid >> 6;

  unsigned wf0[21], wf1[21];
#pragma unroll
  for (int kk = 0; kk < 21; ++kk){
    wf0[kk] = wpk[kk * 128 + lane];
    wf1[kk] = wpk[kk * 128 + 64 + lane];
  }

  const int gw = blockIdx.x * 4 + w, nw = gridDim.x * 4;
  const int q = N_ATOMS / nw, rr = N_ATOMS % nw;
  const int a0 = gw * q + (gw < rr ? gw : rr);
  const int a1 = a0 + q + (gw < rr ? 1 : 0);
  float s0 = 0.f, s1 = 0.f, q0 = 0.f, q1 = 0.f;
  int cur = 0;
  unsigned pn = 0;
  if (a0 < a1){ ISSUE_ATOM(a0, 0); }
  for (int a = a0; a < a1; ++a){
    // wait for current buffer's 14 DMA + p-load (issued prev iter / prologue).
    // Steady state: the 12 newest outstanding are prev body's gated stores.
    if (a == a0 || !STORE) asm volatile("s_waitcnt vmcnt(0)" ::: "memory");
    else                   asm volatile("s_waitcnt vmcnt(12)" ::: "memory");
    unsigned pc = pn;
    const int au = __builtin_amdgcn_readfirstlane(a);
    const int base = au * M_NBR;
    const int anext = (a + 1 < a1) ? (a + 1) : a;
    ISSUE_ATOM(anext, cur ^ 1);            // fly under this atom's compute
    const float* fr = s_frow + (w * 2 + cur) * 1280;
    const unsigned* fr2 = (const unsigned*)(fr + 512);
    const float p10 = unlo(pc), p11 = unhi(pc);
    GBODY(0) GBODY(1) GBODY(2) GBODY(3) GBODY(4) GBODY(5)
    GBODY(6) GBODY(7) GBODY(8) GBODY(9) GBODY(10) GBODY(11)
    cur ^= 1;
  }
  // drain ALL pending DMA (dummy last issue included) before aliasing s_frow
  asm volatile("s_waitcnt vmcnt(0)" ::: "memory");
  __syncthreads();
  float* red = s_frow;
  red[w * 256 + lane]        = s0;
  red[w * 256 + 64 + lane]   = s1;
  red[w * 256 + 128 + lane]  = q0;
  red[w * 256 + 192 + lane]  = q1;
  __syncthreads();
  float v = red[tid] + red[256 + tid] + red[512 + tid] + red[768 + tid];
  part1[blockIdx.x * 256 + tid] = v;
}

// ---- parallel BN1 finish: 128 blocks (r21 proven) --------------------------
__global__ __launch_bounds__(256) void k_stats_fin(
    const float* __restrict__ part1, const float* __restrict__ bn1_g,
    const float* __restrict__ bn1_b, float* __restrict__ stats1)
{
  __shared__ float red[256];
  const int c = blockIdx.x;
  const int t = threadIdx.x;
  float s = 0.f, q = 0.f;
#pragma unroll
  for (int i = t; i < NBLK_ST; i += 256){
    s += part1[(size_t)i * 256 + c];
    q += part1[(size_t)i * 256 + 128 + c];
  }
  red[t] = s; __syncthreads();
  for (int o = 128; o > 0; o >>= 1){ if (t < o) red[t] += red[t + o]; __syncthreads(); }
  float sumv = red[0]; __syncthreads();
  red[t] = q; __syncthreads();
  for (int o = 128; o > 0; o >>= 1){ if (t < o) red[t] += red[t + o]; __syncthreads(); }
  if (t == 0){
    const float inv = 1.f / (float)(N_ATOMS * M_NBR);
    float mu = sumv * inv;
    float var = red[0] * inv - mu * mu;
    float sc = bn1_g[c] * rsqrtf(var + EPSV);
    stats1[c] = sc;
    stats1[128 + c] = bn1_b[c] - mu * sc;
  }
}

// ---------------- K4a (gated path): streaming BN1+gate+sum ------------------
__global__ __launch_bounds__(256) void k_reduce_g(
    const unsigned* __restrict__ gated, const float* __restrict__ stats1,
    float* __restrict__ nbr_sumed, float* __restrict__ part2)
{
  __shared__ float red[512];
  const int tid = threadIdx.x, lane = tid & 63, w = tid >> 6;
  const float sc0 = stats1[lane],       sc1 = stats1[64 + lane];
  const float tc0 = stats1[128 + lane], tc1 = stats1[192 + lane];
  const int wg = blockIdx.x * 4 + w, nw = gridDim.x * 4;
  float bs = 0.f, bq = 0.f;
  for (int a = wg; a < N_ATOMS; a += nw){
    const size_t base = (size_t)a * M_NBR * 64 + lane;
    float acc = 0.f;
#pragma unroll
    for (int m = 0; m < M_NBR; ++m){
      unsigned gv = gated[base + m * 64];
      acc += sigmoidf(unlo(gv) * sc0 + tc0) * softplusf(unhi(gv) * sc1 + tc1);
    }
    nbr_sumed[(size_t)a * 64 + lane] = acc;
    bs += acc; bq += acc * acc;
  }
  red[w * 128 + lane]      = bs;
  red[w * 128 + 64 + lane] = bq;
  __syncthreads();
  if (tid < 128){
    float v = red[tid] + red[128 + tid] + red[256 + tid] + red[384 + tid];
    part2[blockIdx.x * 128 + tid] = v;
  }
}

// ---------------- K4b (fallback): recompute g, BN1, gate, sum ---------------
#define LOADRW(MM) unsigned rw##MM = proj2p[(size_t)__builtin_amdgcn_readfirstlane(jrow[MM]) * 64 + lane];
#define GBODYR(MM) { \
    const float* frow = nbr_fea + (size_t)(base + MM) * NBR_FEA; \
    float g0 = p10 + unlo(rw##MM); \
    float g1 = p11 + unhi(rw##MM); \
    _Pragma("unroll") \
    for (int k = 0; k < NBR_FEA; ++k){ \
      float aa = frow[k]; \
      g0 += aa * unlo(wbp[k]); \
      g1 += aa * unhi(wbp[k]); \
    } \
    acc += sigmoidf(g0 * sc0 + tc0) * softplusf(g1 * sc1 + tc1); }

__global__ __launch_bounds__(256) void k_reduce_r(
    const float* __restrict__ nbr_fea, const int* __restrict__ nbr_idx,
    const float* __restrict__ fc_w, const unsigned* __restrict__ proj1p,
    const unsigned* __restrict__ proj2p, const float* __restrict__ stats1,
    float* __restrict__ nbr_sumed, float* __restrict__ part2)
{
  __shared__ float red[512];
  const int tid = threadIdx.x, lane = tid & 63, w = tid >> 6;
  unsigned wbp[NBR_FEA];
#pragma unroll
  for (int k = 0; k < NBR_FEA; ++k){
    float w0 = fc_w[(128 + k) * 128 + lane];
    float w1 = fc_w[(128 + k) * 128 + 64 + lane];
    wbp[k] = pack2(w0, w1);
  }
  const float sc0 = stats1[lane],       sc1 = stats1[64 + lane];
  const float tc0 = stats1[128 + lane], tc1 = stats1[192 + lane];
  const int gw = blockIdx.x * 4 + w, nw = gridDim.x * 4;
  const int q = N_ATOMS / nw, rr = N_ATOMS % nw;
  const int a0 = gw * q + (gw < rr ? gw : rr);
  const int a1 = a0 + q + (gw < rr ? 1 : 0);
  float bs = 0.f, bq = 0.f;
  for (int a = a0; a < a1; ++a){
    const int au = __builtin_amdgcn_readfirstlane(a);
    const int base = au * M_NBR;
    const int* jrow = nbr_idx + base;
    unsigned p1v = proj1p[(size_t)au * 64 + lane];
    LOADRW(0) LOADRW(1) LOADRW(2) LOADRW(3) LOADRW(4) LOADRW(5)
    LOADRW(6) LOADRW(7) LOADRW(8) LOADRW(9) LOADRW(10) LOADRW(11)
    const float p10 = unlo(p1v), p11 = unhi(p1v);
    float acc = 0.f;
    GBODYR(0) GBODYR(1) GBODYR(2) GBODYR(3) GBODYR(4) GBODYR(5)
    GBODYR(6) GBODYR(7) GBODYR(8) GBODYR(9) GBODYR(10) GBODYR(11)
    nbr_sumed[(size_t)au * 64 + lane] = acc;
    bs += acc; bq += acc * acc;
  }
  red[w * 128 + lane]      = bs;
  red[w * 128 + 64 + lane] = bq;
  __syncthreads();
  if (tid < 128){
    float v = red[tid] + red[128 + tid] + red[256 + tid] + red[384 + tid];
    part2[blockIdx.x * 128 + tid] = v;
  }
}

// ---- parallel BN2 finish: 64 blocks (r21 proven) ---------------------------
__global__ __launch_bounds__(256) void k_red_fin(
    const float* __restrict__ part2, const float* __restrict__ bn2_g,
    const float* __restrict__ bn2_b, float* __restrict__ stats2)
{
  __shared__ float red[256];
  const int c = blockIdx.x;
  const int t = threadIdx.x;
  float s = 0.f, q = 0.f;
#pragma unroll
  for (int i = t; i < NBLK_MAIN; i += 256){
    s += part2[(size_t)i * 128 + c];
    q += part2[(size_t)i * 128 + 64 + c];
  }
  red[t] = s; __syncthreads();
  for (int o = 128; o > 0; o >>= 1){ if (t < o) red[t] += red[t + o]; __syncthreads(); }
  float sumv = red[0]; __syncthreads();
  red[t] = q; __syncthreads();
  for (int o = 128; o > 0; o >>= 1){ if (t < o) red[t] += red[t + o]; __syncthreads(); }
  if (t == 0){
    const float inv = 1.f / (float)N_ATOMS;
    float mu = sumv * inv;
    float var = red[0] * inv - mu * mu;
    float sc = bn2_g[c] * rsqrtf(var + EPSV);
    stats2[c] = sc;
    stats2[64 + c] = bn2_b[c] - mu * sc;
  }
}

// ---------------- K5: out = softplus(atom_tf + BN2(nbr_sumed)), float4 ------
__global__ __launch_bounds__(256) void k_final(
    const float* __restrict__ atom_tf, const float* __restrict__ ns,
    const float* __restrict__ stats2, float* __restrict__ out)
{
  int i = blockIdx.x * 256 + threadIdx.x;   // one float4 per thread
  if (i >= N_ATOMS * 16) return;            // N*64/4
  int c0 = (i * 4) & 63;
  float4 av = ((const float4*)atom_tf)[i];
  float4 nv = ((const float4*)ns)[i];
  float4 o;
  o.x = softplusf(av.x + nv.x * stats2[c0]     + stats2[64 + c0]);
  o.y = softplusf(av.y + nv.y * stats2[c0 + 1] + stats2[64 + c0 + 1]);
  o.z = softplusf(av.z + nv.z * stats2[c0 + 2] + stats2[64 + c0 + 2]);
  o.w = softplusf(av.w + nv.w * stats2[c0 + 3] + stats2[64 + c0 + 3]);
  ((float4*)out)[i] = o;
}

extern "C" void kernel_launch(void* const* d_in, const int* in_sizes, int n_in,
                              void* d_out, int out_size, void* d_ws, size_t ws_size,
                              hipStream_t stream)
{
  const float* atom_in = (const float*)d_in[0];
  const float* nbr_fea = (const float*)d_in[1];
  const float* adj     = (const float*)d_in[2];
  const float* w1 = (const float*)d_in[3];
  const float* b1 = (const float*)d_in[4];
  const float* w2 = (const float*)d_in[5];
  const float* b2 = (const float*)d_in[6];
  const float* tln1_g = (const float*)d_in[7];
  const float* tln1_b = (const float*)d_in[8];
  const float* tln2_g = (const float*)d_in[9];
  const float* tln2_b = (const float*)d_in[10];
  const float* fc_w = (const float*)d_in[11];
  const float* fc_b = (const float*)d_in[12];
  const float* bn1_g = (const float*)d_in[13];
  const float* bn1_b = (const float*)d_in[14];
  const float* bn2_g = (const float*)d_in[15];
  const float* bn2_b = (const float*)d_in[16];
  const int* nbr_idx = (const int*)d_in[17];
  const int* cidx    = (const int*)d_in[18];
  float* out = (float*)d_out;

  char* ws = (char*)d_ws;
  size_t off = 0;
  float* atom_tf = (float*)(ws + off);    off += (size_t)N_ATOMS * 64 * 4;
  unsigned* proj1p = (unsigned*)(ws + off); off += (size_t)N_ATOMS * 64 * 4;
  unsigned* proj2p = (unsigned*)(ws + off); off += (size_t)N_ATOMS * 64 * 4;
  float* nbr_sumed = (float*)(ws + off);  off += (size_t)N_ATOMS * 64 * 4;
  float* part1 = (float*)(ws + off);      off += (size_t)NBLK_MAIN * 256 * 4;
  float* stats1 = (float*)(ws + off);     off += 256 * 4;
  float* part2 = (float*)(ws + off);      off += (size_t)NBLK_MAIN * 128 * 4;
  float* stats2 = (float*)(ws + off);     off += 128 * 4;
  unsigned* wpk = (unsigned*)(ws + off);  off += 21 * 128 * 4;
  unsigned* gated = (unsigned*)(ws + off);
  const size_t need_gated = off + (size_t)N_ATOMS * M_NBR * 64 * 4;
  const bool use_gated = (ws_size >= need_gated);

  float* ln1 = nbr_sumed;

  k_prep<<<11, 256, 0, stream>>>(fc_w, wpk);
  k_attn<<<B_CRY, 512, 0, stream>>>(atom_in, adj, tln1_g, tln1_b, cidx, ln1);
  k_ff<<<2048, 256, 0, stream>>>(ln1, atom_in, cidx, w1, b1, w2, b2,
      tln2_g, tln2_b, fc_w, fc_b, atom_tf, proj1p, proj2p);
  if (use_gated){
    k_stats<1><<<NBLK_ST, 256, 0, stream>>>(nbr_fea, nbr_idx, wpk, proj1p,
        proj2p, part1, gated);
    k_stats_fin<<<128, 256, 0, stream>>>(part1, bn1_g, bn1_b, stats1);
    k_reduce_g<<<NBLK_MAIN, 256, 0, stream>>>(gated, stats1, nbr_sumed, part2);
  } else {
    k_stats<0><<<NBLK_ST, 256, 0, stream>>>(nbr_fea, nbr_idx, wpk, proj1p,
        proj2p, part1, gated);
    k_stats_fin<<<128, 256, 0, stream>>>(part1, bn1_g, bn1_b, stats1);
    k_reduce_r<<<NBLK_MAIN, 256, 0, stream>>>(nbr_fea, nbr_idx, fc_w, proj1p,
        proj2p, stats1, nbr_sumed, part2);
  }
  k_red_fin<<<64, 256, 0, stream>>>(part2, bn2_g, bn2_b, stats2);
  k_final<<<(N_ATOMS * 16 + 255) / 256, 256, 0, stream>>>(atom_tf, nbr_sumed, stats2, out);
}

// Round 27
// 336.752 us; speedup vs baseline: 1.1715x; 1.0297x over previous
//
#include <hip/hip_runtime.h>
#include <math.h>

#define N_ATOMS 60000
#define M_NBR   12
#define D_FEA   64
#define NBR_FEA 41
#define B_CRY   1200
#define NA_CRY  50
#define EPSV    1e-5f

#define NBLK_MAIN 2048   // blocks for k_stats (4 waves each)

typedef _Float16 h2 __attribute__((ext_vector_type(2)));
#define CVTPK(a, b) __builtin_bit_cast(h2, __builtin_amdgcn_cvt_pkrtz((a), (b)))

__device__ __forceinline__ float wsum(float v){
#pragma unroll
  for (int o = 32; o > 0; o >>= 1) v += __shfl_xor(v, o, 64);
  return v;
}
__device__ __forceinline__ float wmax64(float v){
#pragma unroll
  for (int o = 32; o > 0; o >>= 1) v = fmaxf(v, __shfl_xor(v, o, 64));
  return v;
}
__device__ __forceinline__ float softplusf(float x){
  return fmaxf(x, 0.f) + __logf(1.f + __expf(-fabsf(x)));
}
__device__ __forceinline__ float sigmoidf(float x){
  return 1.f / (1.f + __expf(-x));
}
// round-to-nearest-even fp32 -> bf16 bits (low 16)
__device__ __forceinline__ unsigned bf16_rne(float x){
  unsigned u = __float_as_uint(x);
  return (u + 0x7fffu + ((u >> 16) & 1u)) >> 16;
}
__device__ __forceinline__ unsigned pack2(float lo, float hi){
  return bf16_rne(lo) | (bf16_rne(hi) << 16);
}
__device__ __forceinline__ float unlo(unsigned u){ return __uint_as_float(u << 16); }
__device__ __forceinline__ float unhi(unsigned u){ return __uint_as_float(u & 0xffff0000u); }

// ---------------- K0: pre-pack bond weights as f16 k-pairs (r23 proven) -----
__global__ __launch_bounds__(256) void k_prep(
    const float* __restrict__ fc_w, unsigned* __restrict__ wpk)
{
  int t = blockIdx.x * 256 + threadIdx.x;
  if (t >= 21 * 128) return;
  int kk = t >> 7, c = t & 127;
  float lo = fc_w[(128 + 2 * kk) * 128 + c];
  float hi = (kk < 20) ? fc_w[(129 + 2 * kk) * 128 + c] : 0.f;
  wpk[t] = __builtin_bit_cast(unsigned, __builtin_amdgcn_cvt_pkrtz(lo, hi));
}

// ---------------- K1a: attention half (phases 1-5) -> ln1 [N,64] ------------
__global__ __launch_bounds__(512, 4) void k_attn(
    const float* __restrict__ atom_in, const float* __restrict__ adj,
    const float* __restrict__ g1v, const float* __restrict__ be1,
    const int* __restrict__ cidx, float* __restrict__ ln1)
{
  __shared__ float s_a[NA_CRY * D_FEA];        // src rows
  __shared__ float s_b[D_FEA * (NA_CRY + 1)];  // srcT(stride 51) / x
  __shared__ float s_c[NA_CRY * D_FEA];        // scores

  const int tid  = threadIdx.x;
  const int b    = blockIdx.x;
  const int lane = tid & 63;
  const int w    = tid >> 6;   // 0..7

  for (int p = tid; p < NA_CRY * D_FEA; p += 512){
    int i = p >> 6, d = p & 63;
    int a = cidx[b * NA_CRY + i];
    float v = atom_in[(size_t)a * D_FEA + d];
    s_a[p] = v;
    s_b[d * (NA_CRY + 1) + i] = v;
  }
  __syncthreads();

  const float scale = 0.125f; // 1/sqrt(64)
  {
    const float* adjb = adj + (size_t)b * NA_CRY * NA_CRY;
    for (int t = tid; t < 625; t += 512){
      int i0 = (t / 25) * 2, j0 = (t % 25) * 2;
      float a00 = 0.f, a01 = 0.f, a10 = 0.f, a11 = 0.f;
#pragma unroll 8
      for (int d = 0; d < D_FEA; ++d){
        float va0 = s_a[i0 * D_FEA + d];
        float va1 = s_a[(i0 + 1) * D_FEA + d];
        float vb0 = s_b[d * (NA_CRY + 1) + j0];
        float vb1 = s_b[d * (NA_CRY + 1) + j0 + 1];
        a00 += va0 * vb0; a01 += va0 * vb1;
        a10 += va1 * vb0; a11 += va1 * vb1;
      }
      s_c[i0 * NA_CRY + j0]           = a00 * scale * adjb[i0 * NA_CRY + j0];
      s_c[i0 * NA_CRY + j0 + 1]       = a01 * scale * adjb[i0 * NA_CRY + j0 + 1];
      s_c[(i0 + 1) * NA_CRY + j0]     = a10 * scale * adjb[(i0 + 1) * NA_CRY + j0];
      s_c[(i0 + 1) * NA_CRY + j0 + 1] = a11 * scale * adjb[(i0 + 1) * NA_CRY + j0 + 1];
    }
  }
  __syncthreads();

  for (int r = w; r < NA_CRY; r += 8){
    float v = (lane < NA_CRY) ? s_c[r * NA_CRY + lane] : -1e30f;
    float mx = wmax64(v);
    float e = (lane < NA_CRY) ? __expf(v - mx) : 0.f;
    float s = wsum(e);
    if (lane < NA_CRY) s_c[r * NA_CRY + lane] = e / s;
  }
  __syncthreads();

  for (int t = tid; t < 25 * D_FEA; t += 512){
    int nh = t >> 6, d = t & 63;
    int n0 = nh * 2, n1 = n0 + 1;
    float x0 = 0.f, x1 = 0.f;
#pragma unroll 10
    for (int m = 0; m < NA_CRY; ++m){
      float sa = s_a[m * D_FEA + d];
      x0 += s_c[n0 * NA_CRY + m] * sa;
      x1 += s_c[n1 * NA_CRY + m] * sa;
    }
    s_b[n0 * D_FEA + d] = s_a[n0 * D_FEA + d] + x0;
    s_b[n1 * D_FEA + d] = s_a[n1 * D_FEA + d] + x1;
  }
  __syncthreads();

  for (int r = w; r < NA_CRY; r += 8){
    float x = s_b[r * D_FEA + lane];
    float mu = wsum(x) * (1.f / 64.f);
    float dx = x - mu;
    float var = wsum(dx * dx) * (1.f / 64.f);
    ln1[(size_t)(b * NA_CRY + r) * D_FEA + lane] =
        dx * rsqrtf(var + EPSV) * g1v[lane] + be1[lane];
  }
}

// ---------------- K1b: FF + LN2 + projections, barrier-free -----------------
__global__ __launch_bounds__(256) void k_ff(
    const float* __restrict__ ln1, const float* __restrict__ atom_in,
    const int* __restrict__ cidx,
    const float* __restrict__ w1, const float* __restrict__ b1,
    const float* __restrict__ w2, const float* __restrict__ b2,
    const float* __restrict__ g2v, const float* __restrict__ be2,
    const float* __restrict__ fc_w, const float* __restrict__ fc_b,
    float* __restrict__ atom_tf, unsigned* __restrict__ proj1p,
    unsigned* __restrict__ proj2p)
{
  __shared__ float sl[4][8][64];
  const int tid = threadIdx.x, lane = tid & 63, w = tid >> 6;
  float (*A)[64] = &sl[w][0];
  float (*Bs)[64] = &sl[w][4];

  const int gw = blockIdx.x * 4 + w, nw = gridDim.x * 4;
  const int NGRP = N_ATOMS / 4;
  for (int g = gw; g < NGRP; g += nw){
    const int r0 = g * 4;
    float ln0 = ln1[(size_t)(r0 + 0) * 64 + lane];
    float ln1v = ln1[(size_t)(r0 + 1) * 64 + lane];
    float ln2 = ln1[(size_t)(r0 + 2) * 64 + lane];
    float ln3 = ln1[(size_t)(r0 + 3) * 64 + lane];
    A[0][lane] = ln0; A[1][lane] = ln1v; A[2][lane] = ln2; A[3][lane] = ln3;
    __builtin_amdgcn_s_waitcnt(0);

    float h0a = 0.f, h1a = 0.f, h2a = 0.f, h3a = 0.f;
    float h0b = 0.f, h1b = 0.f, h2b = 0.f, h3b = 0.f;
#pragma unroll 8
    for (int k = 0; k < D_FEA; k += 2){
      float wv0 = w1[k * D_FEA + lane];
      float wv1 = w1[(k + 1) * D_FEA + lane];
      h0a += A[0][k] * wv0; h0b += A[0][k + 1] * wv1;
      h1a += A[1][k] * wv0; h1b += A[1][k + 1] * wv1;
      h2a += A[2][k] * wv0; h2b += A[2][k + 1] * wv1;
      h3a += A[3][k] * wv0; h3b += A[3][k + 1] * wv1;
    }
    float bb1 = b1[lane];
    float h0 = fmaxf(bb1 + h0a + h0b, 0.f);
    float h1 = fmaxf(bb1 + h1a + h1b, 0.f);
    float h2 = fmaxf(bb1 + h2a + h2b, 0.f);
    float h3 = fmaxf(bb1 + h3a + h3b, 0.f);
    Bs[0][lane] = h0; Bs[1][lane] = h1; Bs[2][lane] = h2; Bs[3][lane] = h3;
    __builtin_amdgcn_s_waitcnt(0);

    float t0a = 0.f, t1a = 0.f, t2a = 0.f, t3a = 0.f;
    float t0b = 0.f, t1b = 0.f, t2b = 0.f, t3b = 0.f;
#pragma unroll 8
    for (int k = 0; k < D_FEA; k += 2){
      float wv0 = w2[k * D_FEA + lane];
      float wv1 = w2[(k + 1) * D_FEA + lane];
      t0a += Bs[0][k] * wv0; t0b += Bs[0][k + 1] * wv1;
      t1a += Bs[1][k] * wv0; t1b += Bs[1][k + 1] * wv1;
      t2a += Bs[2][k] * wv0; t2b += Bs[2][k + 1] * wv1;
      t3a += Bs[3][k] * wv0; t3b += Bs[3][k + 1] * wv1;
    }
    float bb2 = b2[lane];
    float t0 = ln0 + bb2 + t0a + t0b;
    float t1 = ln1v + bb2 + t1a + t1b;
    float t2 = ln2 + bb2 + t2a + t2b;
    float t3 = ln3 + bb2 + t3a + t3b;

    float gv = g2v[lane], bv = be2[lane];
#define LN2ROW(TT, JJ) { \
      float mu = wsum(TT) * (1.f / 64.f); \
      float dx = (TT) - mu; \
      float var = wsum(dx * dx) * (1.f / 64.f); \
      float res = dx * rsqrtf(var + EPSV) * gv + bv; \
      atom_tf[(size_t)(r0 + JJ) * 64 + lane] = res; \
      A[JJ][lane] = res; }
    LN2ROW(t0, 0) LN2ROW(t1, 1) LN2ROW(t2, 2) LN2ROW(t3, 3)
#undef LN2ROW

    const int ga0 = cidx[r0], ga1 = cidx[r0 + 1], ga2 = cidx[r0 + 2], ga3 = cidx[r0 + 3];
    Bs[0][lane] = atom_in[(size_t)ga0 * 64 + lane];
    Bs[1][lane] = atom_in[(size_t)ga1 * 64 + lane];
    Bs[2][lane] = atom_in[(size_t)ga2 * 64 + lane];
    Bs[3][lane] = atom_in[(size_t)ga3 * 64 + lane];
    __builtin_amdgcn_s_waitcnt(0);

    const float bb0 = fc_b[lane], bb6 = fc_b[64 + lane];
    float A1 = bb0, A2 = bb6, A3 = 0.f, A4 = 0.f;
    float B1 = bb0, B2 = bb6, B3 = 0.f, B4 = 0.f;
    float C1 = bb0, C2 = bb6, C3 = 0.f, C4 = 0.f;
    float D1 = bb0, D2 = bb6, D3 = 0.f, D4 = 0.f;
#pragma unroll 4
    for (int k = 0; k < D_FEA; ++k){
      float w0 = fc_w[k * 128 + lane];
      float w6 = fc_w[k * 128 + 64 + lane];
      float v0 = fc_w[(64 + k) * 128 + lane];
      float v6 = fc_w[(64 + k) * 128 + 64 + lane];
      float ta = A[0][k], tb = A[1][k], tc = A[2][k], td = A[3][k];
      float sa = Bs[0][k], sb = Bs[1][k], sc = Bs[2][k], sd = Bs[3][k];
      A1 += ta * w0; A2 += ta * w6; A3 += sa * v0; A4 += sa * v6;
      B1 += tb * w0; B2 += tb * w6; B3 += sb * v0; B4 += sb * v6;
      C1 += tc * w0; C2 += tc * w6; C3 += sc * v0; C4 += sc * v6;
      D1 += td * w0; D2 += td * w6; D3 += sd * v0; D4 += sd * v6;
    }
    proj1p[(size_t)(r0 + 0) * 64 + lane] = pack2(A1, A2);
    proj1p[(size_t)(r0 + 1) * 64 + lane] = pack2(B1, B2);
    proj1p[(size_t)(r0 + 2) * 64 + lane] = pack2(C1, C2);
    proj1p[(size_t)(r0 + 3) * 64 + lane] = pack2(D1, D2);
    proj2p[(size_t)ga0 * 64 + lane] = pack2(A3, A4);
    proj2p[(size_t)ga1 * 64 + lane] = pack2(B3, B4);
    proj2p[(size_t)ga2 * 64 + lane] = pack2(C3, C4);
    proj2p[(size_t)ga3 * 64 + lane] = pack2(D3, D4);
  }
}

// ---------------- K3: BN1 stats + store pre-BN g (bf16x2) -------------------
// FINAL (r24 config, best measured): dot2 inner loop (1 cvt + 2 fdot2 per
// k-pair), weights pre-packed by k_prep (42 resident u32), features via 2x
// 16B global_load_lds double-buffer, 12 proj2p gathers drained by vmcnt(2).
// Pipelining the gathers was tried twice and lost: registers spill (r25,
// +55us), LDS-DMA halves occupancy (r26, +18us). TLP at 8 blocks/CU is the
// cheapest latency-hiding for this kernel.
#define LOADRW(MM) unsigned rw##MM = proj2p[(size_t)__builtin_amdgcn_readfirstlane(jrow[MM]) * 64 + lane];

#define STAGE(AA, BUF) { \
    const float* srcp = nbr_fea + (size_t)(AA) * (M_NBR * NBR_FEA); \
    float* dstp = s_frow + (w * 2 + (BUF)) * 512; \
    __builtin_amdgcn_global_load_lds(srcp + lane * 4, dstp, 16, 0, 0); \
    if (lane < 59) \
      __builtin_amdgcn_global_load_lds(srcp + 256 + lane * 4, dstp + 256, 16, 0, 0); \
  }

#define GBODY(MM) { \
    float g0 = p10 + unlo(rw##MM); \
    float g1 = p11 + unhi(rw##MM); \
    const float* frm = fr + MM * NBR_FEA; \
    _Pragma("unroll") \
    for (int kk = 0; kk < 20; ++kk){ \
      h2 fa = CVTPK(frm[2 * kk], frm[2 * kk + 1]); \
      g0 = __builtin_amdgcn_fdot2(fa, __builtin_bit_cast(h2, wf0[kk]), g0, false); \
      g1 = __builtin_amdgcn_fdot2(fa, __builtin_bit_cast(h2, wf1[kk]), g1, false); \
    } \
    { h2 fa = CVTPK(frm[40], 0.f); \
      g0 = __builtin_amdgcn_fdot2(fa, __builtin_bit_cast(h2, wf0[20]), g0, false); \
      g1 = __builtin_amdgcn_fdot2(fa, __builtin_bit_cast(h2, wf1[20]), g1, false); } \
    if (STORE) gated[(size_t)(base + MM) * 64 + lane] = pack2(g0, g1); \
    s0 += g0; q0 += g0 * g0; \
    s1 += g1; q1 += g1 * g1; }

template<int STORE>
__global__ __launch_bounds__(256) void k_stats(
    const float* __restrict__ nbr_fea, const int* __restrict__ nbr_idx,
    const unsigned* __restrict__ wpk, const unsigned* __restrict__ proj1p,
    const unsigned* __restrict__ proj2p, float* __restrict__ part1,
    unsigned* __restrict__ gated)
{
  __shared__ float s_frow[4 * 2 * 512];  // staging; reduction aliases after drain
  const int tid = threadIdx.x, lane = tid & 63, w = tid >> 6;

  unsigned wf0[21], wf1[21];
#pragma unroll
  for (int kk = 0; kk < 21; ++kk){
    wf0[kk] = wpk[kk * 128 + lane];
    wf1[kk] = wpk[kk * 128 + 64 + lane];
  }

  const int gw = blockIdx.x * 4 + w, nw = gridDim.x * 4;
  const int q = N_ATOMS / nw, rr = N_ATOMS % nw;
  const int a0 = gw * q + (gw < rr ? gw : rr);
  const int a1 = a0 + q + (gw < rr ? 1 : 0);
  float s0 = 0.f, s1 = 0.f, q0 = 0.f, q1 = 0.f;
  int cur = 0;
  if (a0 < a1){ STAGE(a0, 0); }
  for (int a = a0; a < a1; ++a){
    const int au = __builtin_amdgcn_readfirstlane(a);
    const int base = au * M_NBR;
    const int* jrow = nbr_idx + base;
    unsigned p1v = proj1p[(size_t)au * 64 + lane];
    LOADRW(0) LOADRW(1) LOADRW(2) LOADRW(3) LOADRW(4) LOADRW(5)
    LOADRW(6) LOADRW(7) LOADRW(8) LOADRW(9) LOADRW(10) LOADRW(11)
    const int anext = (a + 1 < a1) ? (a + 1) : a;
    STAGE(anext, cur ^ 1);
    asm volatile("s_waitcnt vmcnt(2)" ::: "memory");
    const float* fr = s_frow + (w * 2 + cur) * 512;
    const float p10 = unlo(p1v), p11 = unhi(p1v);
    GBODY(0) GBODY(1) GBODY(2) GBODY(3) GBODY(4) GBODY(5)
    GBODY(6) GBODY(7) GBODY(8) GBODY(9) GBODY(10) GBODY(11)
    cur ^= 1;
  }
  // drain ALL pending loads (incl. dummy last-stage) before aliasing s_frow
  asm volatile("s_waitcnt vmcnt(0)" ::: "memory");
  __syncthreads();
  float* red = s_frow;
  red[w * 256 + lane]        = s0;
  red[w * 256 + 64 + lane]   = s1;
  red[w * 256 + 128 + lane]  = q0;
  red[w * 256 + 192 + lane]  = q1;
  __syncthreads();
  float v = red[tid] + red[256 + tid] + red[512 + tid] + red[768 + tid];
  part1[blockIdx.x * 256 + tid] = v;
}

// ---- parallel BN1 finish: 128 blocks (r21 proven) --------------------------
__global__ __launch_bounds__(256) void k_stats_fin(
    const float* __restrict__ part1, const float* __restrict__ bn1_g,
    const float* __restrict__ bn1_b, float* __restrict__ stats1)
{
  __shared__ float red[256];
  const int c = blockIdx.x;
  const int t = threadIdx.x;
  float s = 0.f, q = 0.f;
#pragma unroll
  for (int i = t; i < NBLK_MAIN; i += 256){
    s += part1[(size_t)i * 256 + c];
    q += part1[(size_t)i * 256 + 128 + c];
  }
  red[t] = s; __syncthreads();
  for (int o = 128; o > 0; o >>= 1){ if (t < o) red[t] += red[t + o]; __syncthreads(); }
  float sumv = red[0]; __syncthreads();
  red[t] = q; __syncthreads();
  for (int o = 128; o > 0; o >>= 1){ if (t < o) red[t] += red[t + o]; __syncthreads(); }
  if (t == 0){
    const float inv = 1.f / (float)(N_ATOMS * M_NBR);
    float mu = sumv * inv;
    float var = red[0] * inv - mu * mu;
    float sc = bn1_g[c] * rsqrtf(var + EPSV);
    stats1[c] = sc;
    stats1[128 + c] = bn1_b[c] - mu * sc;
  }
}

// ---------------- K4a (gated path): streaming BN1+gate+sum ------------------
__global__ __launch_bounds__(256) void k_reduce_g(
    const unsigned* __restrict__ gated, const float* __restrict__ stats1,
    float* __restrict__ nbr_sumed, float* __restrict__ part2)
{
  __shared__ float red[512];
  const int tid = threadIdx.x, lane = tid & 63, w = tid >> 6;
  const float sc0 = stats1[lane],       sc1 = stats1[64 + lane];
  const float tc0 = stats1[128 + lane], tc1 = stats1[192 + lane];
  const int wg = blockIdx.x * 4 + w, nw = gridDim.x * 4;
  float bs = 0.f, bq = 0.f;
  for (int a = wg; a < N_ATOMS; a += nw){
    const size_t base = (size_t)a * M_NBR * 64 + lane;
    float acc = 0.f;
#pragma unroll
    for (int m = 0; m < M_NBR; ++m){
      unsigned gv = gated[base + m * 64];
      acc += sigmoidf(unlo(gv) * sc0 + tc0) * softplusf(unhi(gv) * sc1 + tc1);
    }
    nbr_sumed[(size_t)a * 64 + lane] = acc;
    bs += acc; bq += acc * acc;
  }
  red[w * 128 + lane]      = bs;
  red[w * 128 + 64 + lane] = bq;
  __syncthreads();
  if (tid < 128){
    float v = red[tid] + red[128 + tid] + red[256 + tid] + red[384 + tid];
    part2[blockIdx.x * 128 + tid] = v;
  }
}

// ---------------- K4b (fallback): recompute g, BN1, gate, sum ---------------
#define LOADRWF(MM) unsigned rw##MM = proj2p[(size_t)__builtin_amdgcn_readfirstlane(jrow[MM]) * 64 + lane];
#define GBODYR(MM) { \
    const float* frow = nbr_fea + (size_t)(base + MM) * NBR_FEA; \
    float g0 = p10 + unlo(rw##MM); \
    float g1 = p11 + unhi(rw##MM); \
    _Pragma("unroll") \
    for (int k = 0; k < NBR_FEA; ++k){ \
      float aa = frow[k]; \
      g0 += aa * unlo(wbp[k]); \
      g1 += aa * unhi(wbp[k]); \
    } \
    acc += sigmoidf(g0 * sc0 + tc0) * softplusf(g1 * sc1 + tc1); }

__global__ __launch_bounds__(256) void k_reduce_r(
    const float* __restrict__ nbr_fea, const int* __restrict__ nbr_idx,
    const float* __restrict__ fc_w, const unsigned* __restrict__ proj1p,
    const unsigned* __restrict__ proj2p, const float* __restrict__ stats1,
    float* __restrict__ nbr_sumed, float* __restrict__ part2)
{
  __shared__ float red[512];
  const int tid = threadIdx.x, lane = tid & 63, w = tid >> 6;
  unsigned wbp[NBR_FEA];
#pragma unroll
  for (int k = 0; k < NBR_FEA; ++k){
    float w0 = fc_w[(128 + k) * 128 + lane];
    float w1 = fc_w[(128 + k) * 128 + 64 + lane];
    wbp[k] = pack2(w0, w1);
  }
  const float sc0 = stats1[lane],       sc1 = stats1[64 + lane];
  const float tc0 = stats1[128 + lane], tc1 = stats1[192 + lane];
  const int gw = blockIdx.x * 4 + w, nw = gridDim.x * 4;
  const int q = N_ATOMS / nw, rr = N_ATOMS % nw;
  const int a0 = gw * q + (gw < rr ? gw : rr);
  const int a1 = a0 + q + (gw < rr ? 1 : 0);
  float bs = 0.f, bq = 0.f;
  for (int a = a0; a < a1; ++a){
    const int au = __builtin_amdgcn_readfirstlane(a);
    const int base = au * M_NBR;
    const int* jrow = nbr_idx + base;
    unsigned p1v = proj1p[(size_t)au * 64 + lane];
    LOADRWF(0) LOADRWF(1) LOADRWF(2) LOADRWF(3) LOADRWF(4) LOADRWF(5)
    LOADRWF(6) LOADRWF(7) LOADRWF(8) LOADRWF(9) LOADRWF(10) LOADRWF(11)
    const float p10 = unlo(p1v), p11 = unhi(p1v);
    float acc = 0.f;
    GBODYR(0) GBODYR(1) GBODYR(2) GBODYR(3) GBODYR(4) GBODYR(5)
    GBODYR(6) GBODYR(7) GBODYR(8) GBODYR(9) GBODYR(10) GBODYR(11)
    nbr_sumed[(size_t)au * 64 + lane] = acc;
    bs += acc; bq += acc * acc;
  }
  red[w * 128 + lane]      = bs;
  red[w * 128 + 64 + lane] = bq;
  __syncthreads();
  if (tid < 128){
    float v = red[tid] + red[128 + tid] + red[256 + tid] + red[384 + tid];
    part2[blockIdx.x * 128 + tid] = v;
  }
}

// ---- parallel BN2 finish: 64 blocks (r21 proven) ---------------------------
__global__ __launch_bounds__(256) void k_red_fin(
    const float* __restrict__ part2, const float* __restrict__ bn2_g,
    const float* __restrict__ bn2_b, float* __restrict__ stats2)
{
  __shared__ float red[256];
  const int c = blockIdx.x;
  const int t = threadIdx.x;
  float s = 0.f, q = 0.f;
#pragma unroll
  for (int i = t; i < NBLK_MAIN; i += 256){
    s += part2[(size_t)i * 128 + c];
    q += part2[(size_t)i * 128 + 64 + c];
  }
  red[t] = s; __syncthreads();
  for (int o = 128; o > 0; o >>= 1){ if (t < o) red[t] += red[t + o]; __syncthreads(); }
  float sumv = red[0]; __syncthreads();
  red[t] = q; __syncthreads();
  for (int o = 128; o > 0; o >>= 1){ if (t < o) red[t] += red[t + o]; __syncthreads(); }
  if (t == 0){
    const float inv = 1.f / (float)N_ATOMS;
    float mu = sumv * inv;
    float var = red[0] * inv - mu * mu;
    float sc = bn2_g[c] * rsqrtf(var + EPSV);
    stats2[c] = sc;
    stats2[64 + c] = bn2_b[c] - mu * sc;
  }
}

// ---------------- K5: out = softplus(atom_tf + BN2(nbr_sumed)), float4 ------
__global__ __launch_bounds__(256) void k_final(
    const float* __restrict__ atom_tf, const float* __restrict__ ns,
    const float* __restrict__ stats2, float* __restrict__ out)
{
  int i = blockIdx.x * 256 + threadIdx.x;   // one float4 per thread
  if (i >= N_ATOMS * 16) return;            // N*64/4
  int c0 = (i * 4) & 63;
  float4 av = ((const float4*)atom_tf)[i];
  float4 nv = ((const float4*)ns)[i];
  float4 o;
  o.x = softplusf(av.x + nv.x * stats2[c0]     + stats2[64 + c0]);
  o.y = softplusf(av.y + nv.y * stats2[c0 + 1] + stats2[64 + c0 + 1]);
  o.z = softplusf(av.z + nv.z * stats2[c0 + 2] + stats2[64 + c0 + 2]);
  o.w = softplusf(av.w + nv.w * stats2[c0 + 3] + stats2[64 + c0 + 3]);
  ((float4*)out)[i] = o;
}

extern "C" void kernel_launch(void* const* d_in, const int* in_sizes, int n_in,
                              void* d_out, int out_size, void* d_ws, size_t ws_size,
                              hipStream_t stream)
{
  const float* atom_in = (const float*)d_in[0];
  const float* nbr_fea = (const float*)d_in[1];
  const float* adj     = (const float*)d_in[2];
  const float* w1 = (const float*)d_in[3];
  const float* b1 = (const float*)d_in[4];
  const float* w2 = (const float*)d_in[5];
  const float* b2 = (const float*)d_in[6];
  const float* tln1_g = (const float*)d_in[7];
  const float* tln1_b = (const float*)d_in[8];
  const float* tln2_g = (const float*)d_in[9];
  const float* tln2_b = (const float*)d_in[10];
  const float* fc_w = (const float*)d_in[11];
  const float* fc_b = (const float*)d_in[12];
  const float* bn1_g = (const float*)d_in[13];
  const float* bn1_b = (const float*)d_in[14];
  const float* bn2_g = (const float*)d_in[15];
  const float* bn2_b = (const float*)d_in[16];
  const int* nbr_idx = (const int*)d_in[17];
  const int* cidx    = (const int*)d_in[18];
  float* out = (float*)d_out;

  char* ws = (char*)d_ws;
  size_t off = 0;
  float* atom_tf = (float*)(ws + off);    off += (size_t)N_ATOMS * 64 * 4;
  unsigned* proj1p = (unsigned*)(ws + off); off += (size_t)N_ATOMS * 64 * 4;
  unsigned* proj2p = (unsigned*)(ws + off); off += (size_t)N_ATOMS * 64 * 4;
  float* nbr_sumed = (float*)(ws + off);  off += (size_t)N_ATOMS * 64 * 4;
  float* part1 = (float*)(ws + off);      off += (size_t)NBLK_MAIN * 256 * 4;
  float* stats1 = (float*)(ws + off);     off += 256 * 4;
  float* part2 = (float*)(ws + off);      off += (size_t)NBLK_MAIN * 128 * 4;
  float* stats2 = (float*)(ws + off);     off += 128 * 4;
  unsigned* wpk = (unsigned*)(ws + off);  off += 21 * 128 * 4;
  unsigned* gated = (unsigned*)(ws + off);
  const size_t need_gated = off + (size_t)N_ATOMS * M_NBR * 64 * 4;
  const bool use_gated = (ws_size >= need_gated);

  float* ln1 = nbr_sumed;

  k_prep<<<11, 256, 0, stream>>>(fc_w, wpk);
  k_attn<<<B_CRY, 512, 0, stream>>>(atom_in, adj, tln1_g, tln1_b, cidx, ln1);
  k_ff<<<2048, 256, 0, stream>>>(ln1, atom_in, cidx, w1, b1, w2, b2,
      tln2_g, tln2_b, fc_w, fc_b, atom_tf, proj1p, proj2p);
  if (use_gated){
    k_stats<1><<<NBLK_MAIN, 256, 0, stream>>>(nbr_fea, nbr_idx, wpk, proj1p,
        proj2p, part1, gated);
    k_stats_fin<<<128, 256, 0, stream>>>(part1, bn1_g, bn1_b, stats1);
    k_reduce_g<<<NBLK_MAIN, 256, 0, stream>>>(gated, stats1, nbr_sumed, part2);
  } else {
    k_stats<0><<<NBLK_MAIN, 256, 0, stream>>>(nbr_fea, nbr_idx, wpk, proj1p,
        proj2p, part1, gated);
    k_stats_fin<<<128, 256, 0, stream>>>(part1, bn1_g, bn1_b, stats1);
    k_reduce_r<<<NBLK_MAIN, 256, 0, stream>>>(nbr_fea, nbr_idx, fc_w, proj1p,
        proj2p, stats1, nbr_sumed, part2);
  }
  k_red_fin<<<64, 256, 0, stream>>>(part2, bn2_g, bn2_b, stats2);
  k_final<<<(N_ATOMS * 16 + 255) / 256, 256, 0, stream>>>(atom_tf, nbr_sumed, stats2, out);
}